// Round 1
// baseline (428.707 us; speedup 1.0000x reference)
//
#include <hip/hip_runtime.h>
#include <stdint.h>

// 3D correlation: x1/x2 (1,32,48,48,48) fp32, D_MAX=4 -> 729 offsets, out fp32 (1,729,48,48,48).
// out[(i*9+j)*9+k][h][w][d] = (1/32) * sum_c x1[c,h,w,d] * x2[c, h+i-4, w+j-4, d+k-4]
//
// R5 changes vs R4 (395 us bench = ~208 us harness poison fill + ~187 us kernel):
//  - software pipeline: chunk ch+1's global loads issued BEFORE compute(ch)
//    (was: after previous compute -> full load latency exposed at each vmcnt(0) drain)
//  - staging decode (magic-divs, masks, base offsets) hoisted out of the chunk loop
//  - X2ROW 56 -> 60 floats (240 B stride): kills the delta-4-row bank alias on win reads,
//    keeps 16B alignment for ds_read_b128
//  - launch_bounds (256,3): cap VGPR ~168 -> 3 blocks/CU (LDS 28.5 KB x 3 fits)

#define HH 48
#define WW 48
#define DD 48
#define PAD 4
#define OD 9
#define WT 4            // w positions per block
#define PP 8            // d positions per thread
#define NDG 6           // 48/8
#define CCH 8           // channels per chunk
#define NCHUNK 4
#define X2ROW 60        // staged x2 d extent, padded (was 56); 15 float4 slots
#define X2POS 15
#define X2W 12          // staged x2 w extent (w0-4..w0+7)
#define NACT 216        // WT*OD*NDG
#define X2_UNITS 1440   // CCH * X2W * X2POS
#define X1_UNITS 384    // CCH * WT * 12
#define HWD (HH * WW * DD)
#define CHSTRIDE (CCH * HWD)

__global__ __launch_bounds__(256, 3) void corr_kernel(
    const float* __restrict__ x1,
    const float* __restrict__ x2,
    float* __restrict__ out) {

  __shared__ __attribute__((aligned(16))) float s_x2[CCH * X2W * X2ROW]; // 22.5 KB
  __shared__ __attribute__((aligned(16))) float s_x1[CCH * WT * DD];     // 6 KB

  const int wt = blockIdx.x;   // 0..11
  const int h  = blockIdx.y;   // 0..47
  const int i  = blockIdx.z;   // 0..8
  const int w0 = wt * WT;
  const int r  = h + i - PAD;
  const int t  = threadIdx.x;
  const bool row_ok = (r >= 0) & (r < HH);

  // compute-thread mapping: t = dg + 6*j + 54*wl (dg fastest -> contiguous d stores)
  const bool active = (t < NACT);
  int wl = 0, j = 0, dg = 0;
  if (active) {
    wl = t / (OD * NDG);
    int rem = t - wl * (OD * NDG);
    j = rem / NDG;
    dg = rem - j * NDG;
  }
  const int d0 = dg * PP;

  // ---------- hoisted staging decode (chunk-invariant) ----------
  // x2 unit: idx -> (c = idx/180, w = (idx%180)/15, pos = idx%15)
  //   pos==0 / pos>=13 are d-halo pads (pure zeros); pos 1..12 -> d = (pos-1)*4
  const int rbase = r * (WW * DD);          // may be garbage if !row_ok; guarded
  uint32_t o2[6];
  bool in2[6];
#pragma unroll
  for (int u = 0; u < 6; ++u) {
    const int idx = t + u * 256;
    const bool have = (u < 5) || (idx < X2_UNITS);
    const int c   = idx / (X2W * X2POS);
    const int rm  = idx - c * (X2W * X2POS);
    const int w   = rm / X2POS;
    const int pos = rm - w * X2POS;
    const int wg  = w0 + w - PAD;
    in2[u] = have & row_ok & ((unsigned)wg < (unsigned)WW) &
             ((unsigned)(pos - 1) < 12u);
    o2[u] = (uint32_t)(c * HWD + rbase + wg * DD + (pos - 1) * 4);
  }
  // x1 unit: idx -> (c = idx/48, lin = idx%48); (w,d) contiguous in global memory
  uint32_t o1[2];
  bool in1[2];
#pragma unroll
  for (int u = 0; u < 2; ++u) {
    const int idx = t + u * 256;
    in1[u] = (u < 1) || (idx < X1_UNITS);
    const int c   = idx / 48;
    const int lin = idx - c * 48;
    o1[u] = (uint32_t)(c * HWD + h * (WW * DD) + w0 * DD + lin * 4);
  }

  float acc[OD][PP];
#pragma unroll
  for (int k = 0; k < OD; ++k)
#pragma unroll
    for (int p = 0; p < PP; ++p) acc[k][p] = 0.0f;

  // ---------- prefetch chunk 0 into registers ----------
  float4 v2[6], v1[2];
#pragma unroll
  for (int u = 0; u < 6; ++u) {
    float4 val = make_float4(0.f, 0.f, 0.f, 0.f);
    if (in2[u]) val = *reinterpret_cast<const float4*>(x2 + o2[u]);
    v2[u] = val;
  }
#pragma unroll
  for (int u = 0; u < 2; ++u) {
    float4 val = make_float4(0.f, 0.f, 0.f, 0.f);
    if (in1[u]) val = *reinterpret_cast<const float4*>(x1 + o1[u]);
    v1[u] = val;
  }

#pragma unroll
  for (int ch = 0; ch < NCHUNK; ++ch) {
    __syncthreads();  // all waves done reading previous chunk's LDS

    // ---------- store regs -> LDS: slot is LINEAR in unit idx ----------
#pragma unroll
    for (int u = 0; u < 6; ++u) {
      const int idx = t + u * 256;
      if ((u < 5) || (idx < X2_UNITS))
        *reinterpret_cast<float4*>(s_x2 + idx * 4) = v2[u];
    }
#pragma unroll
    for (int u = 0; u < 2; ++u) {
      const int idx = t + u * 256;
      if ((u < 1) || (idx < X1_UNITS))
        *reinterpret_cast<float4*>(s_x1 + idx * 4) = v1[u];
    }
    __syncthreads();

    // ---------- issue NEXT chunk's global loads before compute ----------
    if (ch + 1 < NCHUNK) {
      const float* b2 = x2 + (size_t)(ch + 1) * CHSTRIDE;
      const float* b1 = x1 + (size_t)(ch + 1) * CHSTRIDE;
#pragma unroll
      for (int u = 0; u < 6; ++u) {
        float4 val = make_float4(0.f, 0.f, 0.f, 0.f);
        if (in2[u]) val = *reinterpret_cast<const float4*>(b2 + o2[u]);
        v2[u] = val;
      }
#pragma unroll
      for (int u = 0; u < 2; ++u) {
        float4 val = make_float4(0.f, 0.f, 0.f, 0.f);
        if (in1[u]) val = *reinterpret_cast<const float4*>(b1 + o1[u]);
        v1[u] = val;
      }
    }

    // ---------- compute (loads above drain at next iteration's barrier) ----------
    if (active) {
      for (int c = 0; c < CCH; ++c) {
        float xv[PP];
        const float* px1 = &s_x1[c * (WT * DD) + wl * DD + d0];
#pragma unroll
        for (int p = 0; p < PP; ++p) xv[p] = px1[p];
        float win[PP + 8];
        const float* px2 = &s_x2[c * (X2W * X2ROW) + (wl + j) * X2ROW + d0];
#pragma unroll
        for (int q = 0; q < PP + 8; ++q) win[q] = px2[q];
#pragma unroll
        for (int k = 0; k < OD; ++k)
#pragma unroll
          for (int p = 0; p < PP; ++p)
            acc[k][p] = fmaf(xv[p], win[p + k], acc[k][p]);
      }
    }
  }

  if (active) {
    const float inv = 1.0f / 32.0f;
    const size_t spat = ((size_t)h * WW + (w0 + wl)) * DD + d0;
#pragma unroll
    for (int k = 0; k < OD; ++k) {
      const int o = (i * OD + j) * OD + k;
      float4 lo = make_float4(acc[k][0] * inv, acc[k][1] * inv,
                              acc[k][2] * inv, acc[k][3] * inv);
      float4 hi = make_float4(acc[k][4] * inv, acc[k][5] * inv,
                              acc[k][6] * inv, acc[k][7] * inv);
      float* dst = out + (size_t)o * (HH * WW * DD) + spat;
      *reinterpret_cast<float4*>(dst)     = lo;
      *reinterpret_cast<float4*>(dst + 4) = hi;
    }
  }
}

extern "C" void kernel_launch(void* const* d_in, const int* in_sizes, int n_in,
                              void* d_out, int out_size, void* d_ws, size_t ws_size,
                              hipStream_t stream) {
  const float* x1 = (const float*)d_in[0];
  const float* x2 = (const float*)d_in[1];
  float* out = (float*)d_out;
  dim3 grid(WW / WT, HH, OD);  // (12, 48, 9)
  corr_kernel<<<grid, 256, 0, stream>>>(x1, x2, out);
}

// Round 2
// 400.094 us; speedup vs baseline: 1.0715x; 1.0715x over previous
//
#include <hip/hip_runtime.h>
#include <stdint.h>

// 3D correlation: x1/x2 (1,32,48,48,48) fp32, D_MAX=4 -> 729 offsets, out fp32 (1,729,48,48,48).
// out[(i*9+j)*9+k][h][w][d] = (1/32) * sum_c x1[c,h,w,d] * x2[c, h+i-4, w+j-4, d+k-4]
//
// R6 vs R5 (222 us kernel; R4 was 187): root cause of R5 regression = reg-staging
// + (256,3) VGPR cap -> spills, and __syncthreads() drains vmcnt(0) so the "pipeline"
// never existed at ISA level. R6 restructures staging entirely:
//  - global_load_lds (no staging VGPRs, no ds_write instrs; LDS slot linear in unit idx)
//  - double-buffered LDS (CCH=4 -> 28.5 KB total), raw s_barrier + counted vmcnt(N)
//    so next-chunk loads stay in flight across the barrier (T3/T4)
//  - pad/halo LDS slots zeroed once; masked lanes never write them
//  - per-wave issue count via __ballot -> exact counted wait on edge blocks
//  - (256,3): 3 blocks/CU (LDS 85.5 KB, ~130 VGPR now that staging regs are gone)

#define HH 48
#define WW 48
#define DD 48
#define PAD 4
#define OD 9
#define WT 4            // w positions per block
#define PP 8            // d positions per thread
#define NDG 6           // 48/8
#define CCH 4           // channels per chunk (= #waves; wave wv stages channel wv)
#define NCHUNK 8
#define X2POS 15        // 16B units per staged x2 row (pos 0,13,14 = zero pads)
#define X2ROW 60        // floats per staged x2 row (d = -4..51 + 4 pad floats)
#define X2W 12          // staged x2 w extent (w0-4 .. w0+7)
#define NACT 216        // WT*OD*NDG
#define X2_FLOATS (CCH * X2W * X2ROW)   // 2880
#define X1_FLOATS (CCH * WT * DD)       // 768
#define HWD (HH * WW * DD)
#define CHFLOATS (CCH * HWD)

#define GLOAD16(gp, lp)                                                  \
  __builtin_amdgcn_global_load_lds(                                      \
      (const __attribute__((address_space(1))) void*)(gp),               \
      (__attribute__((address_space(3))) void*)(lp), 16, 0, 0)

__global__ __launch_bounds__(256, 3) void corr_kernel(
    const float* __restrict__ x1,
    const float* __restrict__ x2,
    float* __restrict__ out) {

  __shared__ __attribute__((aligned(16))) float s_x2[2][X2_FLOATS]; // 22.5 KB
  __shared__ __attribute__((aligned(16))) float s_x1[2][X1_FLOATS]; // 6 KB

  const int wt = blockIdx.x;   // 0..11
  const int h  = blockIdx.y;   // 0..47
  const int i  = blockIdx.z;   // 0..8
  const int w0 = wt * WT;
  const int r  = h + i - PAD;
  const int t  = threadIdx.x;
  const int lane = t & 63;
  const int wv   = t >> 6;     // wave id 0..3 == staged channel within chunk
  const bool row_ok = (r >= 0) & (r < HH);

  // ---- zero both buffers once (halo slots stay 0 forever: masked lanes never write)
  {
    const float4 z = make_float4(0.f, 0.f, 0.f, 0.f);
    float* p2 = &s_x2[0][0];
    for (int s = t; s < (2 * X2_FLOATS) / 4; s += 256)
      reinterpret_cast<float4*>(p2)[s] = z;
    float* p1 = &s_x1[0][0];
    for (int s = t; s < (2 * X1_FLOATS) / 4; s += 256)
      reinterpret_cast<float4*>(p1)[s] = z;
  }

  // ---- staging decode, chunk-invariant ----
  // x2: wave wv stages its channel's 180 units via u=0..2; unit-in-channel m = u*64+lane
  //     m -> (w = m/15, pos = m%15); pos 1..12 -> global d = (pos-1)*4
  uint32_t o2[3];
  bool m2[3];
#pragma unroll
  for (int u = 0; u < 3; ++u) {
    const int m   = u * 64 + lane;
    const int w   = m / 15;
    const int pos = m - w * 15;
    const int wg  = w0 + w - PAD;
    m2[u] = (m < 180) & row_ok & ((unsigned)wg < (unsigned)WW) &
            ((unsigned)(pos - 1) < 12u);
    o2[u] = (uint32_t)(wv * HWD + r * (WW * DD) + wg * DD + (pos - 1) * 4);
  }
  // x1: wave wv stages its channel's 48 units (lane<48); (w,d) contiguous in global
  const bool m1 = (lane < 48);
  const uint32_t o1 = (uint32_t)(wv * HWD + h * (WW * DD) + w0 * DD + lane * 4);

  // exact per-wave global_load_lds count per chunk (for the counted vmcnt wait)
  int nvm = 1;  // x1 group always issues
#pragma unroll
  for (int u = 0; u < 3; ++u) nvm += (__ballot(m2[u]) != 0ull) ? 1 : 0;

  // ---- compute-thread mapping: t = dg + 6*j + 54*wl ----
  const bool active = (t < NACT);
  int wl = 0, j = 0, dg = 0;
  if (active) {
    wl = t / (OD * NDG);
    int rem = t - wl * (OD * NDG);
    j = rem / NDG;
    dg = rem - j * NDG;
  }
  const int d0 = dg * PP;

  float acc[OD][PP];
#pragma unroll
  for (int k = 0; k < OD; ++k)
#pragma unroll
    for (int p = 0; p < PP; ++p) acc[k][p] = 0.0f;

  __syncthreads();  // zeros visible before any global_load_lds write lands

  // ---- prologue: stage chunk 0 -> buffer 0 ----
#pragma unroll
  for (int u = 0; u < 3; ++u)
    if (m2[u]) GLOAD16(x2 + o2[u], &s_x2[0][(wv * 180 + u * 64) * 4]);
  if (m1) GLOAD16(x1 + o1, &s_x1[0][(wv * 48) * 4]);

  for (int ch = 0; ch < NCHUNK; ++ch) {
    const int b = ch & 1;
    if (ch + 1 < NCHUNK) {
      // issue next chunk into the other buffer, then drain ONLY current chunk
      const float* g2 = x2 + (size_t)(ch + 1) * CHFLOATS;
      const float* g1 = x1 + (size_t)(ch + 1) * CHFLOATS;
#pragma unroll
      for (int u = 0; u < 3; ++u)
        if (m2[u]) GLOAD16(g2 + o2[u], &s_x2[b ^ 1][(wv * 180 + u * 64) * 4]);
      if (m1) GLOAD16(g1 + o1, &s_x1[b ^ 1][(wv * 48) * 4]);
      switch (nvm) {  // leave next chunk's nvm loads in flight
        case 4: asm volatile("s_waitcnt vmcnt(4)" ::: "memory"); break;
        case 3: asm volatile("s_waitcnt vmcnt(3)" ::: "memory"); break;
        case 2: asm volatile("s_waitcnt vmcnt(2)" ::: "memory"); break;
        default: asm volatile("s_waitcnt vmcnt(1)" ::: "memory"); break;
      }
    } else {
      asm volatile("s_waitcnt vmcnt(0)" ::: "memory");
    }
    __builtin_amdgcn_s_barrier();       // all waves' current-chunk loads landed
    __builtin_amdgcn_sched_barrier(0);  // keep LDS reads below the barrier

    if (active) {
#pragma unroll
      for (int c = 0; c < CCH; ++c) {
        const float* px1 = &s_x1[b][c * (WT * DD) + wl * DD + d0];
        float xv[PP];
#pragma unroll
        for (int q = 0; q < 2; ++q) {
          const float4 v = *reinterpret_cast<const float4*>(px1 + q * 4);
          xv[q * 4 + 0] = v.x; xv[q * 4 + 1] = v.y;
          xv[q * 4 + 2] = v.z; xv[q * 4 + 3] = v.w;
        }
        const float* px2 = &s_x2[b][c * (X2W * X2ROW) + (wl + j) * X2ROW + d0];
        float win[PP + 8];
#pragma unroll
        for (int q = 0; q < 4; ++q) {
          const float4 v = *reinterpret_cast<const float4*>(px2 + q * 4);
          win[q * 4 + 0] = v.x; win[q * 4 + 1] = v.y;
          win[q * 4 + 2] = v.z; win[q * 4 + 3] = v.w;
        }
#pragma unroll
        for (int k = 0; k < OD; ++k)
#pragma unroll
          for (int p = 0; p < PP; ++p)
            acc[k][p] = fmaf(xv[p], win[p + k], acc[k][p]);
      }
    }
    __builtin_amdgcn_sched_barrier(0);  // keep reads above barrier2
    __builtin_amdgcn_s_barrier();       // buffer b free for ch+2's loads
    __builtin_amdgcn_sched_barrier(0);  // keep next issue below barrier2
  }

  if (active) {
    const float inv = 1.0f / 32.0f;
    const size_t spat = ((size_t)h * WW + (w0 + wl)) * DD + d0;
#pragma unroll
    for (int k = 0; k < OD; ++k) {
      const int o = (i * OD + j) * OD + k;
      float4 lo = make_float4(acc[k][0] * inv, acc[k][1] * inv,
                              acc[k][2] * inv, acc[k][3] * inv);
      float4 hi = make_float4(acc[k][4] * inv, acc[k][5] * inv,
                              acc[k][6] * inv, acc[k][7] * inv);
      float* dst = out + (size_t)o * (HH * WW * DD) + spat;
      *reinterpret_cast<float4*>(dst)     = lo;
      *reinterpret_cast<float4*>(dst + 4) = hi;
    }
  }
}

extern "C" void kernel_launch(void* const* d_in, const int* in_sizes, int n_in,
                              void* d_out, int out_size, void* d_ws, size_t ws_size,
                              hipStream_t stream) {
  const float* x1 = (const float*)d_in[0];
  const float* x2 = (const float*)d_in[1];
  float* out = (float*)d_out;
  dim3 grid(WW / WT, HH, OD);  // (12, 48, 9)
  corr_kernel<<<grid, 256, 0, stream>>>(x1, x2, out);
}